// Round 1
// baseline (412.431 us; speedup 1.0000x reference)
//
#include <hip/hip_runtime.h>

#define BB 32
#define SS 4096
#define HH 512
#define HALF 2

// ws layout: wpar[BB*8] floats (c, w0..w4, pad, pad), then ipar[BB*4] ints (left, rend, len, pad)

__global__ __launch_bounds__(256) void prep_kernel(
    const float* __restrict__ dh, const float* __restrict__ enc,
    const float* __restrict__ Wp, const float* __restrict__ bp,
    const float* __restrict__ Wa, const int* __restrict__ lens,
    float* __restrict__ wpar, int* __restrict__ ipar)
{
    int b = blockIdx.x;
    int tid = threadIdx.x;
    __shared__ float s_dh[HH];
    __shared__ float s_q[HH];
    __shared__ float red[256];
    __shared__ float s_scores[8];
    __shared__ int s_left, s_right, s_rend;

    for (int i = tid; i < HH; i += 256) s_dh[i] = dh[b * HH + i];
    __syncthreads();

    // position network: sigmoid(dh . Wp + bp) * S
    float p = 0.f;
    for (int i = tid; i < HH; i += 256) p += s_dh[i] * Wp[i];
    red[tid] = p;
    __syncthreads();
    for (int o = 128; o > 0; o >>= 1) {
        if (tid < o) red[tid] += red[tid + o];
        __syncthreads();
    }
    if (tid == 0) {
        float x = red[0] + bp[0];
        float sig = 1.f / (1.f + expf(-x));
        float pos = sig * (float)SS;
        int center = (int)floorf(pos);
        int left = center - HALF; if (left < 0) left = 0;
        int right = center + HALF + 1; if (right > SS) right = SS;
        int len = lens[b];
        s_left = left;
        s_right = right;
        s_rend = (right < len) ? right : len;
    }
    __syncthreads();

    // q = dh @ Wa  (q[j] = sum_i dh[i] * Wa[i*H + j]); coalesced across j
    for (int j = tid; j < HH; j += 256) {
        float acc = 0.f;
        #pragma unroll 8
        for (int i = 0; i < HH; ++i) acc += s_dh[i] * Wa[i * HH + j];
        s_q[j] = acc;
    }
    __syncthreads();

    // window scores: one wave per score position
    int wave = tid >> 6, lane = tid & 63;
    const float* encb = enc + (size_t)b * SS * HH;
    for (int wi = wave; wi < 5; wi += 4) {
        int s = s_left + wi;
        float sc = 0.f;
        if (s < s_right) {
            const float* row = encb + (size_t)s * HH;
            for (int i = lane; i < HH; i += 64) sc += s_q[i] * row[i];
        }
        #pragma unroll
        for (int o = 32; o > 0; o >>= 1) sc += __shfl_down(sc, o);
        if (lane == 0) s_scores[wi] = sc;
    }
    __syncthreads();

    if (tid == 0) {
        int len = lens[b];
        int nwin = s_rend - s_left; if (nwin < 0) nwin = 0;   // window ∩ valid count
        int nonwin = len - nwin;                              // valid positions scoring 0
        float m = (nonwin > 0) ? 0.f : -3.0e38f;
        for (int i = 0; i < nwin; ++i) m = fmaxf(m, s_scores[i]);
        float e0 = expf(-m);
        float Z = (float)nonwin * e0;
        float wv[5];
        #pragma unroll
        for (int i = 0; i < 5; ++i) wv[i] = 0.f;
        for (int i = 0; i < nwin; ++i) { wv[i] = expf(s_scores[i] - m); Z += wv[i]; }
        float inv = 1.f / Z;
        wpar[b * 8 + 0] = e0 * inv;                 // baseline weight c
        #pragma unroll
        for (int i = 0; i < 5; ++i) wpar[b * 8 + 1 + i] = wv[i] * inv;
        ipar[b * 4 + 0] = s_left;
        ipar[b * 4 + 1] = s_rend;
        ipar[b * 4 + 2] = len;
    }
}

__global__ __launch_bounds__(256) void weights_kernel(
    const float* __restrict__ wpar, const int* __restrict__ ipar,
    float* __restrict__ wout)
{
    int idx = blockIdx.x * 256 + threadIdx.x;   // grid covers BB*SS exactly
    int b = idx >> 12;          // / 4096
    int s = idx & (SS - 1);
    int left = ipar[b * 4 + 0];
    int rend = ipar[b * 4 + 1];
    int len  = ipar[b * 4 + 2];
    float w;
    if (s >= len) w = 0.f;
    else if (s >= left && s < rend) w = wpar[b * 8 + 1 + (s - left)];
    else w = wpar[b * 8];
    wout[idx] = w;
}

#define CS 64   // rows per chunk

__global__ __launch_bounds__(256) void context_kernel(
    const float* __restrict__ enc, const float* __restrict__ wpar,
    const int* __restrict__ ipar, float* __restrict__ ctx)
{
    const int nchunks = SS / CS;            // 64
    int b = blockIdx.x / nchunks;
    int chunk = blockIdx.x % nchunks;
    int len = ipar[b * 4 + 2];
    int s0 = chunk * CS;
    if (s0 >= len) return;                  // uniform per block
    int s1 = s0 + CS; if (s1 > len) s1 = len;
    int left = ipar[b * 4 + 0];
    int rend = ipar[b * 4 + 1];
    float c = wpar[b * 8];

    int tid = threadIdx.x;
    int col = tid & 127;                    // float4 column
    int rp = tid >> 7;                      // row parity: 0/1
    const float4* enc4 = (const float4*)(enc + (size_t)b * SS * HH);

    float4 acc = make_float4(0.f, 0.f, 0.f, 0.f);
    for (int s = s0 + rp; s < s1; s += 2) {
        float w = c;
        if (s >= left && s < rend) w = wpar[b * 8 + 1 + (s - left)];
        float4 v = enc4[(size_t)s * (HH / 4) + col];
        acc.x += w * v.x; acc.y += w * v.y; acc.z += w * v.z; acc.w += w * v.w;
    }

    __shared__ float4 part[128];
    if (rp == 1) part[col] = acc;
    __syncthreads();
    if (rp == 0) {
        float4 o = part[col];
        acc.x += o.x; acc.y += o.y; acc.z += o.z; acc.w += o.w;
        float* dst = ctx + b * HH + col * 4;
        atomicAdd(dst + 0, acc.x);
        atomicAdd(dst + 1, acc.y);
        atomicAdd(dst + 2, acc.z);
        atomicAdd(dst + 3, acc.w);
    }
}

extern "C" void kernel_launch(void* const* d_in, const int* in_sizes, int n_in,
                              void* d_out, int out_size, void* d_ws, size_t ws_size,
                              hipStream_t stream)
{
    const float* dh   = (const float*)d_in[0];
    const float* enc  = (const float*)d_in[1];
    const float* Wp   = (const float*)d_in[2];
    const float* bp   = (const float*)d_in[3];
    const float* Wa   = (const float*)d_in[4];
    const int*   lens = (const int*)d_in[5];

    float* ctx  = (float*)d_out;                 // [B, H]
    float* wout = (float*)d_out + BB * HH;       // [B, S]

    float* wpar = (float*)d_ws;
    int*   ipar = (int*)((char*)d_ws + BB * 8 * sizeof(float));

    // context is accumulated with atomics -> zero it (d_ws/d_out are poisoned each call)
    hipMemsetAsync(d_out, 0, BB * HH * sizeof(float), stream);

    prep_kernel<<<BB, 256, 0, stream>>>(dh, enc, Wp, bp, Wa, lens, wpar, ipar);
    weights_kernel<<<BB * SS / 256, 256, 0, stream>>>(wpar, ipar, wout);
    context_kernel<<<BB * (SS / CS), 256, 0, stream>>>(enc, wpar, ipar, ctx);
}

// Round 2
// 376.548 us; speedup vs baseline: 1.0953x; 1.0953x over previous
//
#include <hip/hip_runtime.h>

#define BB 32
#define SS 4096
#define HH 512
#define HALF 2
#define CS 64   // rows per context chunk

// ws layout: wpar[BB*8] floats (c, w0..w4, pad, pad), then ipar[BB*4] ints (left, rend, len, pad)

__global__ __launch_bounds__(512) void prep_kernel(
    const float* __restrict__ dh, const float* __restrict__ enc,
    const float* __restrict__ Wp, const float* __restrict__ bp,
    const float* __restrict__ Wa, const int* __restrict__ lens,
    float* __restrict__ wpar, int* __restrict__ ipar, float* __restrict__ ctx)
{
    int b = blockIdx.x;
    int tid = threadIdx.x;            // 0..511, HH == 512
    __shared__ float s_dh[HH];
    __shared__ float s_q[HH];
    __shared__ float red[512];
    __shared__ float s_scores[8];
    __shared__ int s_left, s_rend;

    // zero the context accumulator for this batch (harness poisons d_out)
    ctx[b * HH + tid] = 0.f;

    s_dh[tid] = dh[b * HH + tid];
    __syncthreads();

    // position network: sigmoid(dh . Wp + bp) * S
    red[tid] = s_dh[tid] * Wp[tid];
    __syncthreads();
    for (int o = 256; o > 0; o >>= 1) {
        if (tid < o) red[tid] += red[tid + o];
        __syncthreads();
    }
    if (tid == 0) {
        float x = red[0] + bp[0];
        float sig = 1.f / (1.f + expf(-x));
        float pos = sig * (float)SS;
        int center = (int)floorf(pos);
        int left = center - HALF; if (left < 0) left = 0;
        int right = center + HALF + 1; if (right > SS) right = SS;
        int len = lens[b];
        s_left = left;
        s_rend = (right < len) ? right : len;
    }
    __syncthreads();

    // q = dh @ Wa  (q[j] = sum_i dh[i] * Wa[i*H + j]); one thread per j, coalesced over j
    {
        float acc = 0.f;
        #pragma unroll 8
        for (int i = 0; i < HH; ++i) acc += s_dh[i] * Wa[i * HH + tid];
        s_q[tid] = acc;
    }
    __syncthreads();

    // window scores: one wave per window position (5 of 8 waves active)
    int wave = tid >> 6, lane = tid & 63;
    if (wave < 5) {
        int s = s_left + wave;
        float sc = 0.f;
        if (s < s_rend) {
            const float* row = enc + (size_t)b * SS * HH + (size_t)s * HH;
            for (int i = lane; i < HH; i += 64) sc += s_q[i] * row[i];
        }
        #pragma unroll
        for (int o = 32; o > 0; o >>= 1) sc += __shfl_down(sc, o);
        if (lane == 0) s_scores[wave] = sc;
    }
    __syncthreads();

    if (tid == 0) {
        int len = lens[b];
        int nwin = s_rend - s_left; if (nwin < 0) nwin = 0;  // window ∩ valid
        int nonwin = len - nwin;                             // valid positions scoring 0
        float m = (nonwin > 0) ? 0.f : -3.0e38f;
        for (int i = 0; i < nwin; ++i) m = fmaxf(m, s_scores[i]);
        float e0 = expf(-m);
        float Z = (float)nonwin * e0;
        float wv[5];
        #pragma unroll
        for (int i = 0; i < 5; ++i) wv[i] = 0.f;
        for (int i = 0; i < nwin; ++i) { wv[i] = expf(s_scores[i] - m); Z += wv[i]; }
        float inv = 1.f / Z;
        wpar[b * 8 + 0] = e0 * inv;               // baseline weight
        #pragma unroll
        for (int i = 0; i < 5; ++i) wpar[b * 8 + 1 + i] = wv[i] * inv;
        ipar[b * 4 + 0] = s_left;
        ipar[b * 4 + 1] = s_rend;
        ipar[b * 4 + 2] = len;
    }
}

// fused: write attention weights for this chunk's rows + accumulate context
__global__ __launch_bounds__(256) void ctxw_kernel(
    const float* __restrict__ enc, const float* __restrict__ wpar,
    const int* __restrict__ ipar, float* __restrict__ ctx,
    float* __restrict__ wout)
{
    int b = blockIdx.x >> 6;                // SS/CS = 64 chunks per batch
    int chunk = blockIdx.x & 63;
    int s0 = chunk * CS;
    int left = ipar[b * 4 + 0];
    int rend = ipar[b * 4 + 1];
    int len  = ipar[b * 4 + 2];
    float c = wpar[b * 8];
    int tid = threadIdx.x;

    // attention weights for rows [s0, s0+CS)
    if (tid < CS) {
        int s = s0 + tid;
        float w;
        if (s >= len) w = 0.f;
        else if (s >= left && s < rend) w = wpar[b * 8 + 1 + (s - left)];
        else w = c;
        wout[b * SS + s] = w;
    }

    if (s0 >= len) return;                  // uniform per block
    int s1 = s0 + CS; if (s1 > len) s1 = len;

    int col = tid & 127;                    // float4 column
    int rp = tid >> 7;                      // row parity
    const float4* enc4 = (const float4*)(enc + (size_t)b * SS * HH);

    float4 acc = make_float4(0.f, 0.f, 0.f, 0.f);
    for (int s = s0 + rp; s < s1; s += 2) {
        float w = c;
        if (s >= left && s < rend) w = wpar[b * 8 + 1 + (s - left)];
        float4 v = enc4[(size_t)s * (HH / 4) + col];
        acc.x += w * v.x; acc.y += w * v.y; acc.z += w * v.z; acc.w += w * v.w;
    }

    __shared__ float4 part[128];
    if (rp == 1) part[col] = acc;
    __syncthreads();
    if (rp == 0) {
        float4 o = part[col];
        acc.x += o.x; acc.y += o.y; acc.z += o.z; acc.w += o.w;
        float* dst = ctx + b * HH + col * 4;
        atomicAdd(dst + 0, acc.x);
        atomicAdd(dst + 1, acc.y);
        atomicAdd(dst + 2, acc.z);
        atomicAdd(dst + 3, acc.w);
    }
}

extern "C" void kernel_launch(void* const* d_in, const int* in_sizes, int n_in,
                              void* d_out, int out_size, void* d_ws, size_t ws_size,
                              hipStream_t stream)
{
    const float* dh   = (const float*)d_in[0];
    const float* enc  = (const float*)d_in[1];
    const float* Wp   = (const float*)d_in[2];
    const float* bp   = (const float*)d_in[3];
    const float* Wa   = (const float*)d_in[4];
    const int*   lens = (const int*)d_in[5];

    float* ctx  = (float*)d_out;                 // [B, H]
    float* wout = (float*)d_out + BB * HH;       // [B, S]

    float* wpar = (float*)d_ws;
    int*   ipar = (int*)((char*)d_ws + BB * 8 * sizeof(float));

    prep_kernel<<<BB, 512, 0, stream>>>(dh, enc, Wp, bp, Wa, lens, wpar, ipar, ctx);
    ctxw_kernel<<<BB * (SS / CS), 256, 0, stream>>>(enc, wpar, ipar, ctx, wout);
}